// Round 13
// baseline (30.911 us; speedup 1.0000x reference)
//
#include <hip/hip_runtime.h>

#define N 512
#define D 128

// ws layout (doubles): rs[2jh*2m][512] (16 KB) | ss[2jh*2m][512] (16 KB)
// Plain stores only — no atomics, no counters (R8/R12's proven structure).

// K1: 512 blocks x 256 threads. b -> m = b>>8, iq = (b>>1)&127, jh = b&1.
// Block computes dist(i, j) for i in [4*iq, +4), j in [256*jh, +256).
// Tile is j-major float4 with XOR slot-swizzle: staging = 8 ds_write_b128,
// compute = 8 ds_read_b128 per chunk per thread (4x fewer LDS instrs than
// R12's scalar transpose tile). Next chunk register-prefetched between the
// barriers so global latency hides under compute. f32 wave-tail (validated
// R12), cross-wave combine in double, plain-store publish.
__global__ __launch_bounds__(256) void gw_dist(
    const float* __restrict__ src, const float* __restrict__ tgt,
    double* __restrict__ rs, double* __restrict__ ss)
{
    __shared__ float4 buf[256 * 8];    // 32 KB: [row j][slot], slot XOR-swizzled
    __shared__ float  redf[4][8];      // [wave][quantity] f32 per-wave sums

    const int b  = blockIdx.x;
    const int m  = b >> 8;             // matrix
    const int iq = (b >> 1) & 127;     // i-quad
    const int jh = b & 1;              // j-half
    const int t  = threadIdx.x;        // local j (0..255)
    const int i0 = iq * 4;
    const int j0 = jh * 256;

    const float*  X  = m ? tgt : src;
    const float4* X4 = reinterpret_cast<const float4*>(X + j0 * D); // [256][32]

    const int jr0 = t >> 3;            // staged-row base (0..31)
    const int s   = t & 7;             // this thread's fixed stage slot

    float a0 = 0.f, a1 = 0.f, a2 = 0.f, a3 = 0.f;
    float4 pre[8];

    // prologue: prefetch chunk 0 (8 rows x this thread's slot)
    #pragma unroll
    for (int p = 0; p < 8; ++p)
        pre[p] = X4[(p * 32 + jr0) * 32 + s];

    for (int c = 0; c < 4; ++c) {      // d-chunk: dims [c*32, c*32+32)
        // ---- write prefetched chunk to LDS; swizzled slot = s ^ (row&7).
        // Write phase (8 lanes): quad = (t&7)^((t>>3)&7) distinct -> no conflict.
        #pragma unroll
        for (int p = 0; p < 8; ++p) {
            int jr = p * 32 + jr0;
            buf[jr * 8 + (s ^ (jr & 7))] = pre[p];
        }
        __syncthreads();

        // ---- prefetch next chunk: issued here, consumed next iteration;
        // latency overlaps the compute below.
        if (c < 3) {
            #pragma unroll
            for (int p = 0; p < 8; ++p)
                pre[p] = X4[(p * 32 + jr0) * 32 + (c + 1) * 8 + s];
        }

        // ---- compute: this thread's row j = t vs 4 wave-uniform i-rows ----
        const int dbase = c * 32;
        const float* r0 = X + (i0 + 0) * D + dbase;
        const float* r1 = X + (i0 + 1) * D + dbase;
        const float* r2 = X + (i0 + 2) * D + dbase;
        const float* r3 = X + (i0 + 3) * D + dbase;

        #pragma unroll
        for (int sl = 0; sl < 8; ++sl) {
            // read LDS[t][sl]: G[t][sl] lives at slot sl^(t&7) (involution).
            // Read phase (8 lanes): quad = sl^(t&7) distinct -> no conflict.
            float4 v = buf[t * 8 + (sl ^ (t & 7))];
            float e;
            e = r0[4 * sl + 0] - v.x; a0 += e * e;
            e = r1[4 * sl + 0] - v.x; a1 += e * e;
            e = r2[4 * sl + 0] - v.x; a2 += e * e;
            e = r3[4 * sl + 0] - v.x; a3 += e * e;
            e = r0[4 * sl + 1] - v.y; a0 += e * e;
            e = r1[4 * sl + 1] - v.y; a1 += e * e;
            e = r2[4 * sl + 1] - v.y; a2 += e * e;
            e = r3[4 * sl + 1] - v.y; a3 += e * e;
            e = r0[4 * sl + 2] - v.z; a0 += e * e;
            e = r1[4 * sl + 2] - v.z; a1 += e * e;
            e = r2[4 * sl + 2] - v.z; a2 += e * e;
            e = r3[4 * sl + 2] - v.z; a3 += e * e;
            e = r0[4 * sl + 3] - v.w; a0 += e * e;
            e = r1[4 * sl + 3] - v.w; a1 += e * e;
            e = r2[4 * sl + 3] - v.w; a2 += e * e;
            e = r3[4 * sl + 3] - v.w; a3 += e * e;
        }

        if (c < 3) __syncthreads();    // protect buf before next overwrite
    }

    // a* are the exact f32 pair-costs (identical math to all validated
    // rounds). Wave-level j-sums in f32 (validated R12: absmax 0.0);
    // cross-wave combine in double.
    float qv[8];
    qv[0] = a0; qv[1] = a1; qv[2] = a2; qv[3] = a3;
    qv[4] = a0 * a0; qv[5] = a1 * a1; qv[6] = a2 * a2; qv[7] = a3 * a3;

    const int wave = t >> 6;
    const int lane = t & 63;
    #pragma unroll
    for (int k = 0; k < 8; ++k) {
        float v = qv[k];
        #pragma unroll
        for (int off = 32; off > 0; off >>= 1)
            v += __shfl_down(v, off, 64);
        if (lane == 0) redf[wave][k] = v;
    }
    __syncthreads();

    if (t == 0) {
        const int base = ((jh << 1) | m) * N + i0;   // [jh][m][i] partials
        #pragma unroll
        for (int k = 0; k < 4; ++k) {
            double rsk = (double)redf[0][k]     + (double)redf[1][k]
                       + (double)redf[2][k]     + (double)redf[3][k];
            double ssk = (double)redf[0][k + 4] + (double)redf[1][k + 4]
                       + (double)redf[2][k + 4] + (double)redf[3][k + 4];
            rs[base + k] = rsk;   // plain stores; visible to K2 at kernel boundary
            ss[base + k] = ssk;
        }
    }
}

// K2: single block combines the 2 j-half partials and finalizes (validated R12).
__global__ __launch_bounds__(512) void gw_finalize(
    const double* __restrict__ rs, const double* __restrict__ ss,
    float* __restrict__ out)
{
    const int i = threadIdx.x;

    // index ((jh<<1)|m)*N + i
    const double rs_s = rs[0 * N + i] + rs[2 * N + i];
    const double rs_t = rs[1 * N + i] + rs[3 * N + i];
    const double ss_s = ss[0 * N + i] + ss[2 * N + i];
    const double ss_t = ss[1 * N + i] + ss[3 * N + i];

    double v = (double)N * (ss_s + ss_t) - 2.0 * rs_s * rs_t;
    #pragma unroll
    for (int off = 32; off > 0; off >>= 1)
        v += __shfl_down(v, off, 64);

    __shared__ double sm[8];
    const int wave = i >> 6;
    const int lane = i & 63;
    if (lane == 0) sm[wave] = v;
    __syncthreads();

    if (i == 0) {
        double total = 0.0;
        #pragma unroll
        for (int w = 0; w < 8; ++w) total += sm[w];
        out[0] = (float)(total / ((double)N * (double)N));
    }
}

extern "C" void kernel_launch(void* const* d_in, const int* in_sizes, int n_in,
                              void* d_out, int out_size, void* d_ws, size_t ws_size,
                              hipStream_t stream) {
    const float* src = (const float*)d_in[0];
    const float* tgt = (const float*)d_in[1];
    float* out = (float*)d_out;

    double* rs = (double*)d_ws;       // [4][512]
    double* ss = rs + 4 * N;          // [4][512]

    gw_dist    <<<dim3(512), dim3(256), 0, stream>>>(src, tgt, rs, ss);
    gw_finalize<<<dim3(1),   dim3(512), 0, stream>>>(rs, ss, out);
}

// Round 14
// 16.307 us; speedup vs baseline: 1.8955x; 1.8955x over previous
//
#include <hip/hip_runtime.h>

#define N 512
#define D 128

// ws layout (doubles): rs[2jh*2m][512] (16 KB) | ss[2jh*2m][512] (16 KB)
// Plain stores only — no atomics, no counters (R8/R12's proven structure).
// This is the validated R12 kernel (16.2 us), reverted after R13's b128
// restructure regressed (see session journal: b128 swizzle bank-phasing
// unverified on gfx950; b32 stride-1 reads are the proven-safe pattern).

__device__ __forceinline__ float wave_reduce_add_f32(float v) {
    #pragma unroll
    for (int off = 32; off > 0; off >>= 1)
        v += __shfl_down(v, off, 64);
    return v;
}

// K1: 512 blocks x 256 threads. b -> m = b>>8, iq = (b>>1)&127, jh = b&1.
// Block computes dist(i, j) for i in [4*iq, +4), j in [256*jh, +256).
// Chunked self-staging (4 chunks of 32 dims, padded scalar transpose tile,
// 32.9 KB -> 2 blocks/CU for cross-block latency hiding). f32 wave-tail,
// cross-wave combine in double, plain-store publish.
__global__ __launch_bounds__(256) void gw_dist(
    const float* __restrict__ src, const float* __restrict__ tgt,
    double* __restrict__ rs, double* __restrict__ ss)
{
    __shared__ float tile[32 * 257];   // 32.9 KB: one 32-d chunk, transposed+padded
    __shared__ float redf[4][8];       // [wave][quantity] f32 per-wave sums

    const int b  = blockIdx.x;
    const int m  = b >> 8;             // matrix
    const int iq = (b >> 1) & 127;     // i-quad
    const int jh = b & 1;              // j-half
    const int t  = threadIdx.x;        // local j (0..255)
    const int i0 = iq * 4;
    const int j0 = jh * 256;

    const float*  X  = m ? tgt : src;
    const float4* X4 = reinterpret_cast<const float4*>(X + j0 * D);

    const int jhome = t >> 3;          // 0..31: staging row covered per pass
    const int d4    = t & 7;           // float4 slot within the 32-d chunk

    float a0 = 0.f, a1 = 0.f, a2 = 0.f, a3 = 0.f;

    for (int c = 0; c < 4; ++c) {      // d-chunk: dims [c*32, c*32+32)
        if (c) __syncthreads();        // protect tile before overwrite

        // ---- stage: 8 passes cover 256 j-rows; 8 lanes/row -> each wave
        // reads full 128B lines (ideal coalescing) ----
        #pragma unroll
        for (int p = 0; p < 8; ++p) {
            int jr = p * 32 + jhome;
            float4 v = X4[jr * 32 + c * 8 + d4];
            tile[(d4 * 4 + 0) * 257 + jr] = v.x;
            tile[(d4 * 4 + 1) * 257 + jr] = v.y;
            tile[(d4 * 4 + 2) * 257 + jr] = v.z;
            tile[(d4 * 4 + 3) * 257 + jr] = v.w;
        }
        __syncthreads();

        // ---- compute 32 dims for this thread's j, against 4 i-rows
        // (wave-uniform addresses -> scalar loads from K$) ----
        const int dbase = c * 32;
        const float* r0 = X + (i0 + 0) * D + dbase;
        const float* r1 = X + (i0 + 1) * D + dbase;
        const float* r2 = X + (i0 + 2) * D + dbase;
        const float* r3 = X + (i0 + 3) * D + dbase;

        #pragma unroll
        for (int dd = 0; dd < 32; ++dd) {
            float v = tile[dd * 257 + t];   // lane stride 1: 2 lanes/bank, free
            float e;
            e = r0[dd] - v; a0 += e * e;
            e = r1[dd] - v; a1 += e * e;
            e = r2[dd] - v; a2 += e * e;
            e = r3[dd] - v; a3 += e * e;
        }
    }

    // a* are the exact f32 pair-costs (identical math to all validated
    // rounds). Wave-level j-sums in f32 (validated R12: absmax 0.0);
    // cross-wave combine in double.
    float qv[8];
    qv[0] = a0; qv[1] = a1; qv[2] = a2; qv[3] = a3;
    qv[4] = a0 * a0; qv[5] = a1 * a1; qv[6] = a2 * a2; qv[7] = a3 * a3;

    const int wave = t >> 6;
    const int lane = t & 63;
    #pragma unroll
    for (int k = 0; k < 8; ++k) {
        float v = wave_reduce_add_f32(qv[k]);
        if (lane == 0) redf[wave][k] = v;
    }
    __syncthreads();

    if (t == 0) {
        const int base = ((jh << 1) | m) * N + i0;   // [jh][m][i] partials
        #pragma unroll
        for (int k = 0; k < 4; ++k) {
            double rsk = (double)redf[0][k]     + (double)redf[1][k]
                       + (double)redf[2][k]     + (double)redf[3][k];
            double ssk = (double)redf[0][k + 4] + (double)redf[1][k + 4]
                       + (double)redf[2][k + 4] + (double)redf[3][k + 4];
            rs[base + k] = rsk;   // plain stores; visible to K2 at kernel boundary
            ss[base + k] = ssk;
        }
    }
}

// K2: single block combines the 2 j-half partials and finalizes (validated R12).
__global__ __launch_bounds__(512) void gw_finalize(
    const double* __restrict__ rs, const double* __restrict__ ss,
    float* __restrict__ out)
{
    const int i = threadIdx.x;

    // index ((jh<<1)|m)*N + i
    const double rs_s = rs[0 * N + i] + rs[2 * N + i];
    const double rs_t = rs[1 * N + i] + rs[3 * N + i];
    const double ss_s = ss[0 * N + i] + ss[2 * N + i];
    const double ss_t = ss[1 * N + i] + ss[3 * N + i];

    double v = (double)N * (ss_s + ss_t) - 2.0 * rs_s * rs_t;
    #pragma unroll
    for (int off = 32; off > 0; off >>= 1)
        v += __shfl_down(v, off, 64);

    __shared__ double sm[8];
    const int wave = i >> 6;
    const int lane = i & 63;
    if (lane == 0) sm[wave] = v;
    __syncthreads();

    if (i == 0) {
        double total = 0.0;
        #pragma unroll
        for (int w = 0; w < 8; ++w) total += sm[w];
        out[0] = (float)(total / ((double)N * (double)N));
    }
}

extern "C" void kernel_launch(void* const* d_in, const int* in_sizes, int n_in,
                              void* d_out, int out_size, void* d_ws, size_t ws_size,
                              hipStream_t stream) {
    const float* src = (const float*)d_in[0];
    const float* tgt = (const float*)d_in[1];
    float* out = (float*)d_out;

    double* rs = (double*)d_ws;       // [4][512]
    double* ss = rs + 4 * N;          // [4][512]

    gw_dist    <<<dim3(512), dim3(256), 0, stream>>>(src, tgt, rs, ss);
    gw_finalize<<<dim3(1),   dim3(512), 0, stream>>>(rs, ss, out);
}